// Round 6
// baseline (260.639 us; speedup 1.0000x reference)
//
#include <hip/hip_runtime.h>
#include <hip/hip_bf16.h>

typedef __bf16 bf16x8 __attribute__((ext_vector_type(8)));
typedef __bf16 bf16x4 __attribute__((ext_vector_type(4)));
typedef float  f32x4  __attribute__((ext_vector_type(4)));

#define MFMA16(a, b, c) __builtin_amdgcn_mfma_f32_16x16x32_bf16((a), (b), (c), 0, 0, 0)

// Problem constants: B=8, N=1024, D=512, H=8, DH=64

// ---------------------------------------------------------------------------
// Kernel 1: fused QKV projection.  y = x @ W^T  for W in {Wq,Wk,Wv}.
// q,k stored [b][h][n][dh] bf16 (q scaled by 0.125); v stored TRANSPOSED
// [b][h][dh][n] bf16.
// ---------------------------------------------------------------------------
__global__ __launch_bounds__(256) void gemm_qkv(
    const float* __restrict__ x,
    const float* __restrict__ Wq, const float* __restrict__ Wk,
    const float* __restrict__ Wv,
    __bf16* __restrict__ qo, __bf16* __restrict__ ko, __bf16* __restrict__ vto)
{
    __shared__ __bf16 As[64][40];
    __shared__ __bf16 Bs[64][40];
    const int tid  = threadIdx.x;
    const int lane = tid & 63;
    const int wid  = tid >> 6;
    const int g    = lane >> 4, l16 = lane & 15;
    const int wr   = wid >> 1,  wc  = wid & 1;
    const int r0   = blockIdx.x * 64;
    const int widx = blockIdx.y >> 3;          // 0=q 1=k 2=v
    const int c0   = (blockIdx.y & 7) * 64;
    const float* W = (widx == 0) ? Wq : (widx == 1 ? Wk : Wv);

    const int sr  = tid >> 3;
    const int scq = tid & 7;

    f32x4 acc[2][2] = {};

    for (int k0 = 0; k0 < 512; k0 += 32) {
        __syncthreads();
#pragma unroll
        for (int j = 0; j < 2; ++j) {
            const int r = sr + 32 * j;
            float4 av = *reinterpret_cast<const float4*>(x + (size_t)(r0 + r) * 512 + k0 + scq * 4);
            float4 bv = *reinterpret_cast<const float4*>(W + (size_t)(c0 + r) * 512 + k0 + scq * 4);
            bf16x4 ap = { (__bf16)av.x, (__bf16)av.y, (__bf16)av.z, (__bf16)av.w };
            bf16x4 bp = { (__bf16)bv.x, (__bf16)bv.y, (__bf16)bv.z, (__bf16)bv.w };
            *reinterpret_cast<bf16x4*>(&As[r][scq * 4]) = ap;
            *reinterpret_cast<bf16x4*>(&Bs[r][scq * 4]) = bp;
        }
        __syncthreads();
        bf16x8 af[2], bfr[2];
#pragma unroll
        for (int rt = 0; rt < 2; ++rt)
            af[rt] = *reinterpret_cast<const bf16x8*>(&As[wr * 32 + rt * 16 + l16][g * 8]);
#pragma unroll
        for (int ct = 0; ct < 2; ++ct)
            bfr[ct] = *reinterpret_cast<const bf16x8*>(&Bs[wc * 32 + ct * 16 + l16][g * 8]);
#pragma unroll
        for (int rt = 0; rt < 2; ++rt)
#pragma unroll
            for (int ct = 0; ct < 2; ++ct)
                acc[rt][ct] = MFMA16(af[rt], bfr[ct], acc[rt][ct]);
    }

    if (widx == 2) {
#pragma unroll
        for (int rt = 0; rt < 2; ++rt)
#pragma unroll
            for (int ct = 0; ct < 2; ++ct) {
                int r = r0 + wr * 32 + rt * 16 + 4 * g;
                int c = c0 + wc * 32 + ct * 16 + l16;
                int b = r >> 10, n = r & 1023, h = c >> 6, dh = c & 63;
                bf16x4 pv = { (__bf16)acc[rt][ct][0], (__bf16)acc[rt][ct][1],
                              (__bf16)acc[rt][ct][2], (__bf16)acc[rt][ct][3] };
                *reinterpret_cast<bf16x4*>(vto + (((size_t)b * 8 + h) * 64 + dh) * 1024 + n) = pv;
            }
    } else {
        __bf16* dst = (widx == 0) ? qo : ko;
        const float scale = (widx == 0) ? 0.125f : 1.0f;
#pragma unroll
        for (int rt = 0; rt < 2; ++rt)
#pragma unroll
            for (int ct = 0; ct < 2; ++ct)
#pragma unroll
                for (int reg = 0; reg < 4; ++reg) {
                    int r = r0 + wr * 32 + rt * 16 + 4 * g + reg;
                    int c = c0 + wc * 32 + ct * 16 + l16;
                    float val = acc[rt][ct][reg] * scale;
                    int b = r >> 10, n = r & 1023, h = c >> 6, dh = c & 63;
                    dst[(((size_t)b * 8 + h) * 1024 + n) * 64 + dh] = (__bf16)val;
                }
    }
}

// ---------------------------------------------------------------------------
// Kernel 2: bias re-tile.  bias[b][n][m][h] f32  ->  biasT bf16 in per-lane
// MFMA fragment order: biasT[b][nt][t][h][lane][k], where for lane l
// (g=l>>4, l15=l&15) and k (ct=k>>2, reg=k&3):
//   n = nt*16 + 4g + reg,  m = t*32 + ct*16 + l15.
// Each block owns a contiguous 512 KB input slab (16 rows) -> purely
// sequential coalesced reads (the DRAM-friendliness experiment), staged via
// LDS, written as fully-coalesced 16B/lane stores.
// ---------------------------------------------------------------------------
__global__ __launch_bounds__(512) void bias_retile(
    const float* __restrict__ bias, __bf16* __restrict__ bT)
{
    __shared__ __bf16 st[16 * 2050];   // [row][f], row stride 2050 (bank spread)
    const int tid = threadIdx.x;
    const int bb  = blockIdx.x >> 6;       // batch
    const int nt  = blockIdx.x & 63;       // n-tile
    const int row = tid >> 5;              // staging: 16 rows x 32 threads
    const int col = tid & 31;
    const int h   = tid >> 6;              // writer: 8 heads x 64 lanes
    const int l   = tid & 63;
    const int g   = l >> 4, l15 = l & 15;
    const float* src = bias + ((size_t)(bb * 1024 + nt * 16 + row)) * 8192;

    for (int mq = 0; mq < 4; ++mq) {
        __syncthreads();
        // stage: 16 rows x 2048 floats (contiguous per row) -> bf16 LDS
#pragma unroll
        for (int q = 0; q < 16; ++q) {
            int f = (col + q * 32) * 4;    // 0..2044 step, x4 floats
            f32x4 v = __builtin_nontemporal_load(
                reinterpret_cast<const f32x4*>(src + mq * 2048 + f));
            bf16x4 c = { (__bf16)v.x, (__bf16)v.y, (__bf16)v.z, (__bf16)v.w };
            *reinterpret_cast<bf16x4*>(&st[row * 2050 + f]) = c;
        }
        __syncthreads();
        // write 8 t-slabs, each 8KB contiguous, 16B per lane
#pragma unroll
        for (int tl = 0; tl < 8; ++tl) {
            bf16x8 o;
#pragma unroll
            for (int k = 0; k < 8; ++k) {
                int r  = 4 * g + (k & 3);
                int ml = tl * 32 + ((k >> 2) << 4) + l15;
                o[k] = st[r * 2050 + ml * 8 + h];
            }
            size_t t = (size_t)mq * 8 + tl;
            *reinterpret_cast<bf16x8*>(
                bT + ((((size_t)bb * 64 + nt) * 32 + t) * 8 + h) * 512 + l * 8) = o;
        }
    }
}

// ---------------------------------------------------------------------------
// Kernel 3: fused flash attention.  8 waves = 8 heads, Q-tile 16 rows,
// grid (8 b, 64 nt).  Bias arrives pre-tiled in fragment order: ONE bf16x8
// register load per wave per m-tile, prefetched one tile ahead.  K prefetched
// one tile ahead.  NO barriers in the main loop (psm is wave-private).
// Fixed-max softmax p = exp(s+bias-16); denominator reduced in epilogue.
// ---------------------------------------------------------------------------
__global__ __launch_bounds__(512, 4) void attn_fused(
    const __bf16* __restrict__ qw, const __bf16* __restrict__ kw,
    const __bf16* __restrict__ vtw, const __bf16* __restrict__ bT,
    __bf16* __restrict__ ow)
{
    __shared__ __bf16 psm[8][16][40];      // per-wave P bounce
    const int tid  = threadIdx.x;
    const int w    = tid >> 6;             // head
    const int lane = tid & 63;
    const int g    = lane >> 4, l16 = lane & 15;
    const int b    = blockIdx.x;
    const int nt   = blockIdx.y;
    const int n0   = nt * 16;
    const size_t bh = (size_t)b * 8 + w;

    bf16x8 qf[2];
#pragma unroll
    for (int kc = 0; kc < 2; ++kc)
        qf[kc] = *reinterpret_cast<const bf16x8*>(
            qw + (bh * 1024 + n0 + l16) * 64 + kc * 32 + g * 8);

    f32x4 o[4] = {};
    float lrun[4] = {0.f, 0.f, 0.f, 0.f};

    // per-lane bias stream: t-stride = 8*512 = 4096 elements
    const __bf16* bslab = bT + (((size_t)(b * 64 + nt) * 32 * 8 + w) * 512) + lane * 8;

    bf16x8 bc = *reinterpret_cast<const bf16x8*>(bslab);
    bf16x8 kf[2][2];
#pragma unroll
    for (int ct = 0; ct < 2; ++ct)
#pragma unroll
        for (int kc = 0; kc < 2; ++kc)
            kf[ct][kc] = *reinterpret_cast<const bf16x8*>(
                kw + (bh * 1024 + ct * 16 + l16) * 64 + kc * 32 + g * 8);

    for (int t = 0; t < 32; ++t) {
        const int m0 = t * 32;

        // prefetch bias fragment for next tile (register, coalesced 1KB/wave)
        bf16x8 bn = *reinterpret_cast<const bf16x8*>(
            bslab + (size_t)(t < 31 ? t + 1 : t) * 4096);

        // V for this tile
        bf16x8 vf[4];
#pragma unroll
        for (int oc = 0; oc < 4; ++oc)
            vf[oc] = *reinterpret_cast<const bf16x8*>(
                vtw + (bh * 64 + oc * 16 + l16) * 1024 + m0 + g * 8);

        // K for next tile
        const int mn = (t < 31) ? m0 + 32 : m0;
        bf16x8 kn[2][2];
#pragma unroll
        for (int ct = 0; ct < 2; ++ct)
#pragma unroll
            for (int kc = 0; kc < 2; ++kc)
                kn[ct][kc] = *reinterpret_cast<const bf16x8*>(
                    kw + (bh * 1024 + mn + ct * 16 + l16) * 64 + kc * 32 + g * 8);

        // QK^T
        f32x4 s[2] = {};
#pragma unroll
        for (int ct = 0; ct < 2; ++ct) {
            s[ct] = MFMA16(qf[0], kf[ct][0], s[ct]);
            s[ct] = MFMA16(qf[1], kf[ct][1], s[ct]);
        }

        // fixed-max softmax with register-resident bias
#pragma unroll
        for (int reg = 0; reg < 4; ++reg) {
            float p0 = __expf(s[0][reg] + (float)bc[reg]     - 16.0f);
            float p1 = __expf(s[1][reg] + (float)bc[4 + reg] - 16.0f);
            lrun[reg] += p0 + p1;
            psm[w][4 * g + reg][l16]      = (__bf16)p0;
            psm[w][4 * g + reg][16 + l16] = (__bf16)p1;
        }

        // wave-local P relayout + PV
        bf16x8 pf = *reinterpret_cast<const bf16x8*>(&psm[w][l16][g * 8]);
#pragma unroll
        for (int oc = 0; oc < 4; ++oc)
            o[oc] = MFMA16(pf, vf[oc], o[oc]);

        bc = bn;
#pragma unroll
        for (int ct = 0; ct < 2; ++ct)
#pragma unroll
            for (int kc = 0; kc < 2; ++kc)
                kf[ct][kc] = kn[ct][kc];
    }

    // epilogue: reduce denominator across the 16 m-lanes
#pragma unroll
    for (int reg = 0; reg < 4; ++reg) {
        float l = lrun[reg];
        l += __shfl_xor(l, 1);
        l += __shfl_xor(l, 2);
        l += __shfl_xor(l, 4);
        l += __shfl_xor(l, 8);
        lrun[reg] = l;
    }

#pragma unroll
    for (int oc = 0; oc < 4; ++oc)
#pragma unroll
        for (int reg = 0; reg < 4; ++reg) {
            int n  = n0 + 4 * g + reg;
            int dh = oc * 16 + l16;
            float val = o[oc][reg] / lrun[reg];
            ow[((size_t)b * 1024 + n) * 512 + w * 64 + dh] = (__bf16)val;
        }
}

// ---------------------------------------------------------------------------
// Kernel 4: output projection.  out = O @ Wm^T + bm
// ---------------------------------------------------------------------------
__global__ __launch_bounds__(256) void gemm_out(
    const __bf16* __restrict__ a, const float* __restrict__ Wm,
    const float* __restrict__ bm, float* __restrict__ out)
{
    __shared__ __bf16 As[64][40];
    __shared__ __bf16 Bs[64][40];
    const int tid  = threadIdx.x;
    const int lane = tid & 63;
    const int wid  = tid >> 6;
    const int g    = lane >> 4, l16 = lane & 15;
    const int wr   = wid >> 1,  wc  = wid & 1;
    const int r0   = blockIdx.x * 64;
    const int c0   = blockIdx.y * 64;

    const int sra = tid >> 2, sca = tid & 3;
    const int srb = tid >> 3, scb = tid & 7;

    f32x4 acc[2][2] = {};
    for (int k0 = 0; k0 < 512; k0 += 32) {
        __syncthreads();
        {
            bf16x8 av = *reinterpret_cast<const bf16x8*>(a + (size_t)(r0 + sra) * 512 + k0 + sca * 8);
            *reinterpret_cast<bf16x8*>(&As[sra][sca * 8]) = av;
#pragma unroll
            for (int j = 0; j < 2; ++j) {
                int r = srb + 32 * j;
                float4 bv = *reinterpret_cast<const float4*>(Wm + (size_t)(c0 + r) * 512 + k0 + scb * 4);
                bf16x4 bp = { (__bf16)bv.x, (__bf16)bv.y, (__bf16)bv.z, (__bf16)bv.w };
                *reinterpret_cast<bf16x4*>(&Bs[r][scb * 4]) = bp;
            }
        }
        __syncthreads();
        bf16x8 af[2], bfr[2];
#pragma unroll
        for (int rt = 0; rt < 2; ++rt)
            af[rt] = *reinterpret_cast<const bf16x8*>(&As[wr * 32 + rt * 16 + l16][g * 8]);
#pragma unroll
        for (int ct = 0; ct < 2; ++ct)
            bfr[ct] = *reinterpret_cast<const bf16x8*>(&Bs[wc * 32 + ct * 16 + l16][g * 8]);
#pragma unroll
        for (int rt = 0; rt < 2; ++rt)
#pragma unroll
            for (int ct = 0; ct < 2; ++ct)
                acc[rt][ct] = MFMA16(af[rt], bfr[ct], acc[rt][ct]);
    }

#pragma unroll
    for (int rt = 0; rt < 2; ++rt)
#pragma unroll
        for (int ct = 0; ct < 2; ++ct)
#pragma unroll
            for (int reg = 0; reg < 4; ++reg) {
                int r = r0 + wr * 32 + rt * 16 + 4 * g + reg;
                int c = c0 + wc * 32 + ct * 16 + l16;
                out[(size_t)r * 512 + c] = acc[rt][ct][reg] + bm[c];
            }
}

// ---------------------------------------------------------------------------
extern "C" void kernel_launch(void* const* d_in, const int* in_sizes, int n_in,
                              void* d_out, int out_size, void* d_ws, size_t ws_size,
                              hipStream_t stream)
{
    const float* x    = (const float*)d_in[0];
    const float* bias = (const float*)d_in[1];
    const float* Wq   = (const float*)d_in[2];
    const float* Wk   = (const float*)d_in[3];
    const float* Wv   = (const float*)d_in[4];
    const float* Wm   = (const float*)d_in[5];
    const float* bm   = (const float*)d_in[6];
    float* out = (float*)d_out;

    const size_t SEG = (size_t)8 * 8 * 1024 * 64;   // 4M elems (8 MB bf16) each
    __bf16* qw  = (__bf16*)d_ws;
    __bf16* kw  = qw + SEG;
    __bf16* vtw = kw + SEG;
    __bf16* ow  = vtw + SEG;
    __bf16* bT  = (__bf16*)((char*)d_ws + ((size_t)64 << 20));  // 128 MB at +64MB

    bias_retile<<<dim3(512), 512, 0, stream>>>(bias, bT);
    gemm_qkv   <<<dim3(128, 24), 256, 0, stream>>>(x, Wq, Wk, Wv, qw, kw, vtw);
    attn_fused <<<dim3(8, 64), 512, 0, stream>>>(qw, kw, vtw, bT, ow);
    gemm_out   <<<dim3(128, 8), 256, 0, stream>>>(ow, Wm, bm, out);
}